// Round 5
// baseline (115.017 us; speedup 1.0000x reference)
//
#include <hip/hip_runtime.h>
#include <hip/hip_bf16.h>

// Problem: B=8, N=4096, H=256, F=6
//   Wt[b][n][h] = sum_f osc[f][h][n] * sin(freq_f * t[b] + phase[f][n])
//   out[b][m][n] = sum_h x[b][m][h] * Wt[b][n][h]
//
// R5: LDS-free, barrier-free GEMM. Both MFMA fragment layouts are "8
// consecutive k per lane, row = lane&15" -> load fragments DIRECTLY from
// global (X as 2x float4 + in-register cvt; Wt as 1x uint4). No
// __syncthreads, no vmcnt(0) drain; depth-1 register prefetch keeps ~8 KB
// in flight per wave. Intra-block A duplication (4 wn-waves share rows) is
// L2-absorbed (block's X tile = 64 KB << 4 MB/XCD L2).

#define B_  8
#define N_  4096
#define H_  256

typedef __attribute__((ext_vector_type(8))) short s8v;   // 8 bf16 (A/B frag)
typedef __attribute__((ext_vector_type(4))) float f4v;   // C/D frag

__global__ __launch_bounds__(256) void build_w(
    const float* __restrict__ osc,     // [6][256][256]  osc[f][h][n]
    const float* __restrict__ t,       // [8][1]
    const float* __restrict__ phase,   // [6][256]       phase[f][n]
    __hip_bfloat16* __restrict__ Wt)   // [8][256][256]  Wt[b][n][h]
{
    const float freqs[6] = {1.f, 2.f, 4.f, 8.f, 7.f, 5.f};
    __shared__ float tr[16 * 68];      // [hlocal][n], stride 68

    const int b  = blockIdx.z;
    const int n0 = blockIdx.y * 64;
    const int h0 = blockIdx.x * 128;
    const int tid = threadIdx.x;

    const float tb = t[b];
    const int nr = (tid & 15) * 4;
    const int hr = tid >> 4;
    float s[6][4];
#pragma unroll
    for (int f = 0; f < 6; ++f)
#pragma unroll
        for (int j = 0; j < 4; ++j)
            s[f][j] = __sinf(freqs[f] * tb + phase[f * 256 + n0 + nr + j]);

    const int nw = tid >> 2;
    const int hw = (tid & 3) * 4;
    __hip_bfloat16* wout = Wt + (size_t)b * 65536 + (size_t)(n0 + nw) * 256 + h0;

    for (int hp = 0; hp < 8; ++hp) {
        const int h = h0 + hp * 16 + hr;
        float4 acc = make_float4(0.f, 0.f, 0.f, 0.f);
#pragma unroll
        for (int f = 0; f < 6; ++f) {
            float4 o = *(const float4*)&osc[f * 65536 + h * 256 + n0 + nr];
            acc.x += o.x * s[f][0];
            acc.y += o.y * s[f][1];
            acc.z += o.z * s[f][2];
            acc.w += o.w * s[f][3];
        }
        __syncthreads();
        *(float4*)&tr[hr * 68 + nr] = acc;
        __syncthreads();
        float v0 = tr[(hw + 0) * 68 + nw];
        float v1 = tr[(hw + 1) * 68 + nw];
        float v2 = tr[(hw + 2) * 68 + nw];
        float v3 = tr[(hw + 3) * 68 + nw];
        union { __hip_bfloat162 h2[2]; unsigned long long q; } cv;
        cv.h2[0] = __float22bfloat162_rn(make_float2(v0, v1));
        cv.h2[1] = __float22bfloat162_rn(make_float2(v2, v3));
        *(unsigned long long*)(wout + hp * 16 + hw) = cv.q;
    }
}

__device__ __forceinline__ s8v cvt_frag(float4 lo, float4 hi) {
    union { __hip_bfloat162 h2[4]; s8v v; } cv;
    cv.h2[0] = __float22bfloat162_rn(make_float2(lo.x, lo.y));
    cv.h2[1] = __float22bfloat162_rn(make_float2(lo.z, lo.w));
    cv.h2[2] = __float22bfloat162_rn(make_float2(hi.x, hi.y));
    cv.h2[3] = __float22bfloat162_rn(make_float2(hi.z, hi.w));
    return cv.v;
}

__global__ __launch_bounds__(512, 4) void gemm(
    const float* __restrict__ X,              // [8][4096][256] fp32
    const __hip_bfloat16* __restrict__ Wt,    // [8][256][256]  bf16 [b][n][h]
    float* __restrict__ out)                  // [8][4096][256] fp32
{
    const int b     = blockIdx.y;
    const int mTile = blockIdx.x;             // 0..63, BM=64, BN=256 (full width)

    const int tid    = threadIdx.x;
    const int lane   = tid & 63;
    const int wave   = tid >> 6;              // 0..7
    const int lane15 = lane & 15;
    const int quad   = lane >> 4;             // 0..3
    const int wm     = wave >> 2;             // 0..1: 32-row band
    const int wn     = wave & 3;              // 0..3: 64-col band

    // per-lane fragment base pointers (row = lane15, k-offset = quad*8)
    const float* pa = X + (size_t)b * N_ * H_
                        + (size_t)(mTile * 64 + wm * 32 + lane15) * H_ + quad * 8;
    const __hip_bfloat16* pb = Wt + (size_t)b * H_ * H_
                        + (size_t)(wn * 64 + lane15) * H_ + quad * 8;
    float* Ob = out + (size_t)b * N_ * H_ + (size_t)(mTile * 64) * H_;

    f4v acc[2][4] = {};

    float4 aLo[2], aHi[2];
    uint4  bc[4];

    // prefetch k0 = 0
#pragma unroll
    for (int mt = 0; mt < 2; ++mt) {
        aLo[mt] = *(const float4*)(pa + mt * 16 * H_);
        aHi[mt] = *(const float4*)(pa + mt * 16 * H_ + 4);
    }
#pragma unroll
    for (int nt = 0; nt < 4; ++nt)
        bc[nt] = *(const uint4*)(pb + nt * 16 * H_);

    for (int it = 0; it < 8; ++it) {
        float4 nLo[2], nHi[2];
        uint4  nB[4];
        if (it < 7) {
            const int k = (it + 1) * 32;
#pragma unroll
            for (int mt = 0; mt < 2; ++mt) {
                nLo[mt] = *(const float4*)(pa + mt * 16 * H_ + k);
                nHi[mt] = *(const float4*)(pa + mt * 16 * H_ + k + 4);
            }
#pragma unroll
            for (int nt = 0; nt < 4; ++nt)
                nB[nt] = *(const uint4*)(pb + nt * 16 * H_ + k);
        }

        s8v af[2];
#pragma unroll
        for (int mt = 0; mt < 2; ++mt)
            af[mt] = cvt_frag(aLo[mt], aHi[mt]);

#pragma unroll
        for (int mt = 0; mt < 2; ++mt)
#pragma unroll
            for (int nt = 0; nt < 4; ++nt)
                acc[mt][nt] = __builtin_amdgcn_mfma_f32_16x16x32_bf16(
                    af[mt], *(const s8v*)&bc[nt], acc[mt][nt], 0, 0, 0);

        if (it < 7) {
#pragma unroll
            for (int mt = 0; mt < 2; ++mt) { aLo[mt] = nLo[mt]; aHi[mt] = nHi[mt]; }
#pragma unroll
            for (int nt = 0; nt < 4; ++nt) bc[nt] = nB[nt];
        }
    }

    // epilogue: C/D layout col=lane15, row=quad*4+reg (verified m89/m91)
#pragma unroll
    for (int mt = 0; mt < 2; ++mt) {
#pragma unroll
        for (int r = 0; r < 4; ++r) {
            int row = wm * 32 + mt * 16 + quad * 4 + r;
            float* po = Ob + (size_t)row * H_ + wn * 64 + lane15;
#pragma unroll
            for (int nt = 0; nt < 4; ++nt)
                po[nt * 16] = acc[mt][nt][r];
        }
    }
}

extern "C" void kernel_launch(void* const* d_in, const int* in_sizes, int n_in,
                              void* d_out, int out_size, void* d_ws, size_t ws_size,
                              hipStream_t stream) {
    const float* x     = (const float*)d_in[0];   // [8][4096][256]
    const float* t     = (const float*)d_in[1];   // [8][1]
    const float* osc   = (const float*)d_in[2];   // [6][256][256]
    const float* phase = (const float*)d_in[3];   // [6][256]
    __hip_bfloat16* Wt = (__hip_bfloat16*)d_ws;   // 1 MB scratch, rebuilt every call
    float* out = (float*)d_out;

    dim3 gw(2, 4, 8);                             // (h-half, n-tile, b) = 64 blocks
    build_w<<<gw, 256, 0, stream>>>(osc, t, phase, Wt);

    dim3 gg(64, 8);                               // (mTile, b) = 512 blocks
    gemm<<<gg, 512, 0, stream>>>(x, Wt, out);
}

// Round 6
// 97.253 us; speedup vs baseline: 1.1827x; 1.1827x over previous
//
#include <hip/hip_runtime.h>
#include <hip/hip_bf16.h>

// Problem: B=8, N=4096, H=256, F=6
//   Wt[b][n][h] = sum_f osc[f][h][n] * sin(freq_f * t[b] + phase[f][n])
//   out[b][m][n] = sum_h x[b][m][h] * Wt[b][n][h]
//
// R6: revert to R4's LDS structure (R5's LDS-free variant regressed 14us on
// request amplification). Single change axis: BK 32->64 — halves barrier
// count (16->8), doubles MFMA per barrier interval, LDS 46 KB keeps
// 2 blocks/CU. Epilogue uses nontemporal stores (out is write-once).

#define B_  8
#define N_  4096
#define H_  256

typedef __attribute__((ext_vector_type(8))) short s8v;   // 8 bf16 (A/B frag)
typedef __attribute__((ext_vector_type(4))) float f4v;   // C/D frag

__global__ __launch_bounds__(256) void build_w(
    const float* __restrict__ osc,     // [6][256][256]  osc[f][h][n]
    const float* __restrict__ t,       // [8][1]
    const float* __restrict__ phase,   // [6][256]       phase[f][n]
    __hip_bfloat16* __restrict__ Wt)   // [8][256][256]  Wt[b][n][h]
{
    const float freqs[6] = {1.f, 2.f, 4.f, 8.f, 7.f, 5.f};
    __shared__ float tr[16 * 68];      // [hlocal][n], stride 68

    const int b  = blockIdx.z;
    const int n0 = blockIdx.y * 64;
    const int h0 = blockIdx.x * 128;
    const int tid = threadIdx.x;

    const float tb = t[b];
    const int nr = (tid & 15) * 4;
    const int hr = tid >> 4;
    float s[6][4];
#pragma unroll
    for (int f = 0; f < 6; ++f)
#pragma unroll
        for (int j = 0; j < 4; ++j)
            s[f][j] = __sinf(freqs[f] * tb + phase[f * 256 + n0 + nr + j]);

    const int nw = tid >> 2;
    const int hw = (tid & 3) * 4;
    __hip_bfloat16* wout = Wt + (size_t)b * 65536 + (size_t)(n0 + nw) * 256 + h0;

    for (int hp = 0; hp < 8; ++hp) {
        const int h = h0 + hp * 16 + hr;
        float4 acc = make_float4(0.f, 0.f, 0.f, 0.f);
#pragma unroll
        for (int f = 0; f < 6; ++f) {
            float4 o = *(const float4*)&osc[f * 65536 + h * 256 + n0 + nr];
            acc.x += o.x * s[f][0];
            acc.y += o.y * s[f][1];
            acc.z += o.z * s[f][2];
            acc.w += o.w * s[f][3];
        }
        __syncthreads();
        *(float4*)&tr[hr * 68 + nr] = acc;
        __syncthreads();
        float v0 = tr[(hw + 0) * 68 + nw];
        float v1 = tr[(hw + 1) * 68 + nw];
        float v2 = tr[(hw + 2) * 68 + nw];
        float v3 = tr[(hw + 3) * 68 + nw];
        union { __hip_bfloat162 h2[2]; unsigned long long q; } cv;
        cv.h2[0] = __float22bfloat162_rn(make_float2(v0, v1));
        cv.h2[1] = __float22bfloat162_rn(make_float2(v2, v3));
        *(unsigned long long*)(wout + hp * 16 + hw) = cv.q;
    }
}

// BK=64: LDS row stride 72 shorts (144 B). Row-to-row bank offset 4 (same
// aliasing class as R4's LDST=40, which measured clean).
#define LDST 72

__global__ __launch_bounds__(512, 4) void gemm(
    const float* __restrict__ X,              // [8][4096][256] fp32
    const __hip_bfloat16* __restrict__ Wt,    // [8][256][256]  bf16 [b][n][h]
    float* __restrict__ out)                  // [8][4096][256] fp32
{
    __shared__ short As[64 * LDST];           // As[m][k]   9.2 KB
    __shared__ short Bs[256 * LDST];          // Bs[n][k]  36.9 KB

    const int b     = blockIdx.y;
    const int mTile = blockIdx.x;             // 0..63, BM=64, BN=256

    const int tid    = threadIdx.x;
    const int lane   = tid & 63;
    const int wave   = tid >> 6;              // 0..7
    const int lane15 = lane & 15;
    const int quad   = lane >> 4;             // 0..3
    const int wm     = wave >> 2;             // 0..1: 32-row band
    const int wn     = wave & 3;              // 0..3: 64-col band

    const float* Xb          = X   + (size_t)b * N_ * H_ + (size_t)mTile * 64 * H_;
    const __hip_bfloat16* Wb = Wt  + (size_t)b * H_ * H_;
    float* Ob                = out + (size_t)b * N_ * H_ + (size_t)mTile * 64 * H_;

    // A staging: 64 rows x 64 k fp32 = 16 KB -> 8 floats/thread (32 B contig)
    const int arow = tid >> 3;                // 0..63
    const int aseg = (tid & 7) * 8;           // 0,8,..,56
    const float* pa = Xb + (size_t)arow * H_ + aseg;

    // B staging: 256 rows x 64 k bf16 = 32 KB -> 32 shorts/thread (64 B contig)
    const int brow = tid >> 1;                // 0..255
    const int bhf  = (tid & 1) * 32;          // 0, 32
    const __hip_bfloat16* pb = Wb + (size_t)brow * H_ + bhf;

    f4v acc[2][4] = {};

    // prefetch iter 0
    float4 a0 = *(const float4*)pa;
    float4 a1 = *(const float4*)(pa + 4);
    uint4  bv0 = *(const uint4*)(pb);
    uint4  bv1 = *(const uint4*)(pb + 8);
    uint4  bv2 = *(const uint4*)(pb + 16);
    uint4  bv3 = *(const uint4*)(pb + 24);

    for (int it = 0; it < 4; ++it) {
        // stage regs -> LDS (A converted fp32->bf16 in-register)
        union { __hip_bfloat162 h2[4]; uint4 q; } cv;
        cv.h2[0] = __float22bfloat162_rn(make_float2(a0.x, a0.y));
        cv.h2[1] = __float22bfloat162_rn(make_float2(a0.z, a0.w));
        cv.h2[2] = __float22bfloat162_rn(make_float2(a1.x, a1.y));
        cv.h2[3] = __float22bfloat162_rn(make_float2(a1.z, a1.w));
        *(uint4*)(&As[arow * LDST + aseg]) = cv.q;
        *(uint4*)(&Bs[brow * LDST + bhf + 0])  = bv0;
        *(uint4*)(&Bs[brow * LDST + bhf + 8])  = bv1;
        *(uint4*)(&Bs[brow * LDST + bhf + 16]) = bv2;
        *(uint4*)(&Bs[brow * LDST + bhf + 24]) = bv3;
        __syncthreads();

        // prefetch iter+1 (overlaps the MFMA section)
        if (it < 3) {
            const int k = (it + 1) * 64;
            a0  = *(const float4*)(pa + k);
            a1  = *(const float4*)(pa + k + 4);
            bv0 = *(const uint4*)(pb + k);
            bv1 = *(const uint4*)(pb + k + 8);
            bv2 = *(const uint4*)(pb + k + 16);
            bv3 = *(const uint4*)(pb + k + 24);
        }

        // two k-halves per iter: frag k = kh*32 + quad*8 + j
#pragma unroll
        for (int kh = 0; kh < 2; ++kh) {
            s8v af[2], bf[4];
#pragma unroll
            for (int mt = 0; mt < 2; ++mt)
                af[mt] = *(const s8v*)(&As[(wm * 32 + mt * 16 + lane15) * LDST + kh * 32 + quad * 8]);
#pragma unroll
            for (int nt = 0; nt < 4; ++nt)
                bf[nt] = *(const s8v*)(&Bs[(wn * 64 + nt * 16 + lane15) * LDST + kh * 32 + quad * 8]);
#pragma unroll
            for (int mt = 0; mt < 2; ++mt)
#pragma unroll
                for (int nt = 0; nt < 4; ++nt)
                    acc[mt][nt] = __builtin_amdgcn_mfma_f32_16x16x32_bf16(
                        af[mt], bf[nt], acc[mt][nt], 0, 0, 0);
        }
        __syncthreads();
    }

    // epilogue: C/D layout col=lane15, row=quad*4+reg; nontemporal (write-once)
#pragma unroll
    for (int mt = 0; mt < 2; ++mt) {
#pragma unroll
        for (int r = 0; r < 4; ++r) {
            int row = wm * 32 + mt * 16 + quad * 4 + r;
            float* po = Ob + (size_t)row * H_ + wn * 64 + lane15;
#pragma unroll
            for (int nt = 0; nt < 4; ++nt)
                __builtin_nontemporal_store(acc[mt][nt][r], po + nt * 16);
        }
    }
}

extern "C" void kernel_launch(void* const* d_in, const int* in_sizes, int n_in,
                              void* d_out, int out_size, void* d_ws, size_t ws_size,
                              hipStream_t stream) {
    const float* x     = (const float*)d_in[0];   // [8][4096][256]
    const float* t     = (const float*)d_in[1];   // [8][1]
    const float* osc   = (const float*)d_in[2];   // [6][256][256]
    const float* phase = (const float*)d_in[3];   // [6][256]
    __hip_bfloat16* Wt = (__hip_bfloat16*)d_ws;   // 1 MB scratch, rebuilt every call
    float* out = (float*)d_out;

    dim3 gw(2, 4, 8);                             // (h-half, n-tile, b) = 64 blocks
    build_w<<<gw, 256, 0, stream>>>(osc, t, phase, Wt);

    dim3 gg(64, 8);                               // (mTile, b) = 512 blocks
    gemm<<<gg, 512, 0, stream>>>(x, Wt, out);
}